// Round 15
// baseline (375.448 us; speedup 1.0000x reference)
//
#include <hip/hip_runtime.h>
#include <math.h>

#define NN 65536
#define NE 1048576
#define HH 128
#define ELEC 32
#define BSZ 128
#define NB 512          // node buckets of 128

typedef unsigned short ushort_t;
typedef __bf16 bf16x8 __attribute__((ext_vector_type(8)));
typedef float f32x16 __attribute__((ext_vector_type(16)));

#define MFMA(A, B, C) __builtin_amdgcn_mfma_f32_32x32x16_bf16(A, B, C, 0, 0, 0)

__device__ __forceinline__ float sigm(float x) { return 1.f / (1.f + __expf(-x)); }
__device__ __forceinline__ float tanh_fast(float x) { return 2.f / (1.f + __expf(-2.f * x)) - 1.f; }

__device__ __forceinline__ float bf2f(ushort_t u) {
    union { unsigned int i; float f; } v; v.i = ((unsigned int)u) << 16; return v.f;
}
__device__ __forceinline__ ushort_t f2bf(float f) {
    union { float f; unsigned int i; } v; v.f = f;
    unsigned int r = (v.i + 0x7fffu + ((v.i >> 16) & 1u)) >> 16;
    return (ushort_t)r;
}

// ---------------- per-block bucket histograms (no memset, no global atomics) ----------------
__global__ __launch_bounds__(256) void k_hist2(const int* __restrict__ dst,
                                               int* __restrict__ bh) {
    __shared__ int hh[NB];
    int t = threadIdx.x;
    hh[t] = 0; hh[t + 256] = 0;
    __syncthreads();
    int e0 = blockIdx.x * 4096;
    #pragma unroll
    for (int i = 0; i < 16; ++i)
        atomicAdd(&hh[dst[e0 + i * 256 + t] >> 7], 1);
    __syncthreads();
    bh[blockIdx.x * NB + t] = hh[t];
    bh[blockIdx.x * NB + t + 256] = hh[t + 256];
}

// sum per-block histograms + exclusive scan of 512 bucket counts
__global__ void k_bscan(const int* __restrict__ bh, int* __restrict__ boffs,
                        int* __restrict__ bcur) {
    __shared__ int s[NB];
    int t = threadIdx.x;          // 512 threads
    int v = 0;
    for (int i = 0; i < 256; ++i) v += bh[i * NB + t];
    s[t] = v;
    __syncthreads();
    for (int d = 1; d < NB; d <<= 1) {
        int u = (t >= d) ? s[t - d] : 0;
        __syncthreads();
        s[t] += u;
        __syncthreads();
    }
    int ex = s[t] - v;
    boffs[t] = ex;
    bcur[t] = ex;
    if (t == NB - 1) boffs[NB] = s[t];
}

// bucket partition: per-(block,bucket) contiguous runs -> ~1x write amplification
__global__ __launch_bounds__(256) void k_bpart(const int* __restrict__ src,
        const int* __restrict__ dst, const float* __restrict__ ea,
        int* __restrict__ bcur, uint2* __restrict__ ebkt) {
    __shared__ int lcnt[NB];
    __shared__ int base[NB];
    __shared__ int lcur[NB];
    int t = threadIdx.x;
    lcnt[t] = 0; lcnt[t + 256] = 0;
    lcur[t] = 0; lcur[t + 256] = 0;
    __syncthreads();
    int e0 = blockIdx.x * 4096;
    #pragma unroll
    for (int i = 0; i < 16; ++i)
        atomicAdd(&lcnt[dst[e0 + i * 256 + t] >> 7], 1);
    __syncthreads();
    {
        int c = lcnt[t];
        base[t] = c ? atomicAdd(&bcur[t], c) : 0;
        c = lcnt[t + 256];
        base[t + 256] = c ? atomicAdd(&bcur[t + 256], c) : 0;
    }
    __syncthreads();
    #pragma unroll
    for (int i = 0; i < 16; ++i) {
        int e = e0 + i * 256 + t;
        int d = dst[e];
        int bk = d >> 7;
        int pos = base[bk] + atomicAdd(&lcur[bk], 1);
        uint2 pk;
        pk.x = (unsigned int)src[e] | ((unsigned int)(d & 127) << 16);
        pk.y = __float_as_uint(ea[e]);
        ebkt[pos] = pk;
    }
}

// bucket -> exact per-node CSC (writes land in bucket's 16KB window, L2-absorbed)
__global__ __launch_bounds__(256) void k_csc(const int* __restrict__ boffs,
        const uint2* __restrict__ ebkt, uint2* __restrict__ epack,
        int* __restrict__ offs) {
    __shared__ int cnt[128];
    __shared__ int s[128];
    __shared__ int base[128];
    int b = blockIdx.x, t = threadIdx.x;
    if (t < 128) cnt[t] = 0;
    __syncthreads();
    int e0 = boffs[b], e1 = boffs[b + 1];
    for (int i = e0 + t; i < e1; i += 256)
        atomicAdd(&cnt[(ebkt[i].x >> 16) & 127], 1);
    __syncthreads();
    if (t < 128) s[t] = cnt[t];
    __syncthreads();
    for (int d = 1; d < 128; d <<= 1) {
        int v = (t < 128 && t >= d) ? s[t - d] : 0;
        __syncthreads();
        if (t < 128) s[t] += v;
        __syncthreads();
    }
    if (t < 128) {
        int bs = e0 + s[t] - cnt[t];    // exclusive scan + bucket base
        base[t] = bs;
        offs[b * 128 + t] = bs;
        cnt[t] = 0;                     // reuse as cur
    }
    if (b == 0 && t == 255) offs[NN] = NE;
    __syncthreads();
    for (int i = e0 + t; i < e1; i += 256) {
        uint2 e = ebkt[i];
        int dl = (e.x >> 16) & 127;
        int pos = base[dl] + atomicAdd(&cnt[dl], 1);
        epack[pos] = e;
    }
}

// ---------------- weight prep + h0 init (fused) ----------------
// b<1024: vp[l][512][256] frag-packed (G folded into k<128 half);
// b<2032: lin1 weight transpose wt[k][c]; else: h0 = pad(x) -> bf16
__global__ void k_prep(const float* __restrict__ wih, const float* __restrict__ whh,
                       const float* __restrict__ gw, const float* __restrict__ l1w,
                       const float* __restrict__ x,
                       ushort_t* __restrict__ vp, float* __restrict__ wt,
                       ushort_t* __restrict__ h) {
    int b = blockIdx.x, t = threadIdx.x;
    if (b < 1024) {
        int i = b * 256 + t;              // l*131072 + rho*256 + k
        int l = i >> 17, r2 = i & 131071;
        int rho = r2 >> 8, k = r2 & 255;
        int q = rho >> 7, g = (rho >> 5) & 3, cc = rho & 31;
        int c = q * 32 + cc;
        float v;
        if (k >= 128) {
            if (g == 0)      v = whh[c * 128 + k - 128];
            else if (g == 1) v = whh[(128 + c) * 128 + k - 128];
            else if (g == 2) v = 0.f;
            else             v = whh[(256 + c) * 128 + k - 128];
        } else if (g == 3) {
            v = 0.f;
        } else {
            int crow = (g == 0) ? c : ((g == 1) ? 128 + c : 256 + c);
            const float* gr = gw + l * 16384 + k * 128;
            const float* wr = wih + crow * 128;
            float s = 0.f;
            for (int j = 0; j < 128; ++j) s = fmaf(gr[j], wr[j], s);
            v = s;
        }
        int ks = k >> 4, lh = (k >> 3) & 1, j = k & 7, lr = cc;
        vp[(size_t)l * 131072 + (size_t)(ks * 16 + q * 4 + g) * 512 + (lh * 32 + lr) * 8 + j] = f2bf(v);
    } else if (b < 2032) {
        int i = (b - 1024) * 256 + t;      // k*128 + c, k<2016
        int k = i >> 7, c = i & 127;
        wt[i] = l1w[c * 2016 + k];
    } else {
        int i = (b - 2032) * 256 + t;      // n*128 + c
        int n = i >> 7, c = i & 127;
        float v = (c < 5) ? x[n * 5 + c] : 0.f;
        h[(size_t)n * 128 + c] = f2bf(v);
    }
}

// ---------------- agg[n] = sum ew * h[esrc] -> bf16 agg[n][c] ----------------
// one wave per node, 4 quarter-wave groups x 4 edges per VMEM inst;
// traffic-bound at L3 random-row ceiling (R14: instruction economy was neutral)
__global__ __launch_bounds__(256) void k_gather(const ushort_t* __restrict__ h,
        const int* __restrict__ offs, const uint2* __restrict__ epack,
        ushort_t* __restrict__ agg) {
    int n = blockIdx.x * 4 + (threadIdx.x >> 6);
    int lane = threadIdx.x & 63;
    int g = lane >> 4;          // quarter-wave group
    int cj = (lane & 15) * 8;   // channel base
    int k0 = offs[n], k1 = offs[n + 1];
    float a[8];
    #pragma unroll
    for (int j = 0; j < 8; ++j) a[j] = 0.f;
    int kmax = k1 - 1;
    for (int k = k0; k < k1; k += 16) {
        #pragma unroll
        for (int st = 0; st < 4; ++st) {
            int ke = k + st * 4 + g;
            uint2 e = epack[ke <= kmax ? ke : kmax];
            float w = (ke < k1) ? __uint_as_float(e.y) : 0.f;
            bf16x8 u = *reinterpret_cast<const bf16x8*>(
                h + (size_t)(e.x & 0xFFFFu) * HH + cj);
            union { bf16x8 v; ushort_t s[8]; } uu; uu.v = u;
            #pragma unroll
            for (int j = 0; j < 8; ++j)
                a[j] = fmaf(w, bf2f(uu.s[j]), a[j]);
        }
    }
    #pragma unroll
    for (int j = 0; j < 8; ++j) {
        a[j] += __shfl_xor(a[j], 16, 64);
        a[j] += __shfl_xor(a[j], 32, 64);
    }
    if (lane < 16) {
        uint4 o;
        o.x = (unsigned int)f2bf(a[0]) | ((unsigned int)f2bf(a[1]) << 16);
        o.y = (unsigned int)f2bf(a[2]) | ((unsigned int)f2bf(a[3]) << 16);
        o.z = (unsigned int)f2bf(a[4]) | ((unsigned int)f2bf(a[5]) << 16);
        o.w = (unsigned int)f2bf(a[6]) | ((unsigned int)f2bf(a[7]) << 16);
        *reinterpret_cast<uint4*>(agg + (size_t)n * 128 + cj) = o;
    }
}

// ---------------- fused GRU via K=256 MFMA GEMM, LDS-double-buffered B ----------------
// block: 512 thr = 8 waves over 64 nodes; wave (q,s): V-rows q*128..+127, nodes s*32..+31.
// V staged per-ks chunk (16KB) into 2x16KB LDS: B becomes ds_read_b128, prefetch of
// chunk ks+1 (2 uint4/thread = 8 VGPRs) overlaps chunk ks MFMAs; vp reads are
// sequential/streaming. acc=64 AGPRs + ~64 VGPRs = 128 -> (512,4);
// (512,8) forces a 64-reg/wave budget and spills the accumulators (41ms, R11).
__global__ __launch_bounds__(512, 4) void k_gru(const ushort_t* __restrict__ vp,
        const ushort_t* __restrict__ agg, ushort_t* __restrict__ h,
        const float* __restrict__ bih, const float* __restrict__ bhh) {
    __shared__ ushort_t lV[2][8192];   // 2 x 16KB
    int t = threadIdx.x;
    int lane = t & 63, w = t >> 6;
    int q = w >> 1, s = w & 1;
    int lr = lane & 31, lh = lane >> 5;
    int n0 = blockIdx.x * 64 + s * 32;
    f32x16 acc[4];
    #pragma unroll
    for (int g = 0; g < 4; ++g)
        #pragma unroll
        for (int r = 0; r < 16; ++r) acc[g][r] = 0.f;

    size_t rowA = (size_t)(n0 + lr) * 128;

    // stage chunk 0 (16KB = 1024 uint4, 512 thr x 2)
    {
        const uint4* gsrc = reinterpret_cast<const uint4*>(vp);
        uint4 p0 = gsrc[t * 2 + 0];
        uint4 p1 = gsrc[t * 2 + 1];
        uint4* ld = reinterpret_cast<uint4*>(lV[0]);
        ld[t * 2 + 0] = p0;
        ld[t * 2 + 1] = p1;
    }
    __syncthreads();

    #pragma unroll
    for (int ks = 0; ks < 16; ++ks) {
        uint4 p0, p1;
        if (ks < 15) {
            const uint4* gsrc = reinterpret_cast<const uint4*>(vp + (ks + 1) * 8192);
            p0 = gsrc[t * 2 + 0];
            p1 = gsrc[t * 2 + 1];
        }
        bf16x8 a;
        if (ks < 8) a = *reinterpret_cast<const bf16x8*>(agg + rowA + ks * 16 + lh * 8);
        else        a = *reinterpret_cast<const bf16x8*>(h + rowA + (ks - 8) * 16 + lh * 8);
        const ushort_t* lbuf = lV[ks & 1];
        #pragma unroll
        for (int g2 = 0; g2 < 4; ++g2) {
            bf16x8 b = *reinterpret_cast<const bf16x8*>(lbuf + (q * 4 + g2) * 512 + lane * 8);
            acc[g2] = MFMA(a, b, acc[g2]);
        }
        if (ks < 15) {
            uint4* ld = reinterpret_cast<uint4*>(lV[(ks + 1) & 1]);
            ld[t * 2 + 0] = p0;
            ld[t * 2 + 1] = p1;
        }
        __syncthreads();   // final iter's barrier also guards epilogue's in-place h write
    }

    int c = q * 32 + lr;
    float brz = bih[c] + bhh[c];
    float bzz = bih[128 + c] + bhh[128 + c];
    float bin = bih[256 + c];
    float bhn = bhh[256 + c];
    #pragma unroll
    for (int r = 0; r < 16; ++r) {
        int node = n0 + (r & 3) + 8 * (r >> 2) + 4 * lh;
        float rg = sigm(acc[0][r] + brz);
        float zg = sigm(acc[1][r] + bzz);
        float nn = tanh_fast(acc[2][r] + bin + rg * (acc[3][r] + bhn));
        size_t idx = (size_t)node * 128 + c;
        float hold = bf2f(h[idx]);
        float hnew = (1.f - zg) * nn + zg * hold;
        h[idx] = f2bf(hnew);
    }
}

// ---------------- relu + rearrange + conv1d(stride2,k3) + relu ----------------
__global__ __launch_bounds__(64) void k_conv(const ushort_t* __restrict__ h,
        const float* __restrict__ cw, const float* __restrict__ cb,
        float* __restrict__ co) {
    __shared__ float tile[16 * 128];
    __shared__ float w[48];
    int be = blockIdx.x;
    int b = be >> 5, e = be & 31;
    int t = threadIdx.x;
    if (t < 48) w[t] = cw[t];
    #pragma unroll
    for (int i = 0; i < 8; ++i) {
        int f = t + i * 64;             // 0..511 groups of 4 channels
        int g = f >> 5, c4 = f & 31;
        size_t idx = (size_t)(b * 512 + g * 32 + e) * 128 + c4 * 4;
        ushort4 vh4 = *reinterpret_cast<const ushort4*>(h + idx);
        float* dst = tile + g * 128 + c4 * 4;
        dst[0] = fmaxf(bf2f(vh4.x), 0.f);
        dst[1] = fmaxf(bf2f(vh4.y), 0.f);
        dst[2] = fmaxf(bf2f(vh4.z), 0.f);
        dst[3] = fmaxf(bf2f(vh4.w), 0.f);
    }
    __syncthreads();
    if (t < 63) {
        float s = cb[0];
        #pragma unroll
        for (int g = 0; g < 16; ++g) {
            const float* p = tile + g * 128 + 2 * t;
            s = fmaf(p[0], w[g * 3 + 0], s);
            s = fmaf(p[1], w[g * 3 + 1], s);
            s = fmaf(p[2], w[g * 3 + 2], s);
        }
        co[b * 2016 + e * 63 + t] = fmaxf(s, 0.f);
    }
}

// ---------------- lin1: split-K partials (no atomics, no memset) ----------------
__global__ __launch_bounds__(128) void k_lin1(const float* __restrict__ co,
        const float* __restrict__ wt, float* __restrict__ fc1p) {
    int b = blockIdx.x >> 3;
    int ks = blockIdx.x & 7;
    int c = threadIdx.x;
    const float* cb_ = co + b * 2016 + ks * 252;
    const float* wb = wt + (ks * 252) * 128 + c;
    float s = 0.f;
    #pragma unroll 4
    for (int k = 0; k < 252; ++k)
        s = fmaf(wb[k * 128], cb_[k], s);
    fc1p[(size_t)ks * (BSZ * 128) + b * 128 + c] = s;
}

// ---------------- lin2 + softmax (sums lin1 partials; bias+relu folded) ----------------
__global__ __launch_bounds__(128) void k_lin2(const float* __restrict__ fc1p,
        const float* __restrict__ l1b, const float* __restrict__ w,
        const float* __restrict__ bias, float* __restrict__ out) {
    int b = threadIdx.x;
    float s0 = bias[0], s1 = bias[1], s2 = bias[2];
    for (int k = 0; k < 128; ++k) {
        float v = 0.f;
        #pragma unroll
        for (int ks = 0; ks < 8; ++ks)
            v += fc1p[(size_t)ks * (BSZ * 128) + b * 128 + k];
        float x = fmaxf(v + l1b[k], 0.f);
        s0 = fmaf(x, w[k], s0);
        s1 = fmaf(x, w[128 + k], s1);
        s2 = fmaf(x, w[256 + k], s2);
    }
    float mx = fmaxf(s0, fmaxf(s1, s2));
    float e0 = __expf(s0 - mx), e1 = __expf(s1 - mx), e2 = __expf(s2 - mx);
    float inv = 1.f / (e0 + e1 + e2);
    out[b * 3 + 0] = e0 * inv;
    out[b * 3 + 1] = e1 * inv;
    out[b * 3 + 2] = e2 * inv;
}

extern "C" void kernel_launch(void* const* d_in, const int* in_sizes, int n_in,
                              void* d_out, int out_size, void* d_ws, size_t ws_size,
                              hipStream_t stream) {
    const float* x   = (const float*)d_in[0];
    const int*   ei  = (const int*)d_in[1];
    const float* ea  = (const float*)d_in[2];
    const float* gw  = (const float*)d_in[4];
    const float* wih = (const float*)d_in[5];
    const float* whh = (const float*)d_in[6];
    const float* bih = (const float*)d_in[7];
    const float* bhh = (const float*)d_in[8];
    const float* cw  = (const float*)d_in[9];
    const float* cb  = (const float*)d_in[10];
    const float* l1w = (const float*)d_in[11];
    const float* l1b = (const float*)d_in[12];
    const float* l2w = (const float*)d_in[13];
    const float* l2b = (const float*)d_in[14];
    float* out = (float*)d_out;

    char* p = (char*)d_ws;
    ushort_t* h   = (ushort_t*)p; p += (size_t)NN * 128 * 2;      // 16.7 MB
    ushort_t* agg = (ushort_t*)p; p += (size_t)NN * 128 * 2;      // 16.7 MB
    ushort_t* vp  = (ushort_t*)p; p += 2 * 512 * 256 * 2;         // frag-packed V (G folded), per layer
    uint2* ebkt   = (uint2*)p;   p += (size_t)NE * 8;             // 8.4 MB
    uint2* epack  = (uint2*)p;   p += (size_t)NE * 8;             // 8.4 MB
    float* wt   = (float*)p; p += 2016 * 128 * 4;                 // lin1 W^T
    float* co   = (float*)p; p += (size_t)BSZ * 2016 * 4;
    float* fc1p = (float*)p; p += 8 * (size_t)BSZ * 128 * 4;      // lin1 split-K partials
    int* bh    = (int*)p; p += 256 * NB * 4;                      // per-block bucket hists
    int* boffs = (int*)p; p += (NB + 1) * 4;
    int* bcur  = (int*)p; p += NB * 4;
    int* offs  = (int*)p; p += (size_t)(NN + 1) * 4;

    const int* src = ei;
    const int* dst = ei + NE;

    k_prep<<<34800, 256, 0, stream>>>(wih, whh, gw, l1w, x, vp, wt, h);
    k_hist2<<<256, 256, 0, stream>>>(dst, bh);
    k_bscan<<<1, 512, 0, stream>>>(bh, boffs, bcur);
    k_bpart<<<256, 256, 0, stream>>>(src, dst, ea, bcur, ebkt);
    k_csc<<<NB, 256, 0, stream>>>(boffs, ebkt, epack, offs);

    for (int layer = 0; layer < 2; ++layer) {
        k_gather<<<NN / 4, 256, 0, stream>>>(h, offs, epack, agg);
        k_gru<<<NN / 64, 512, 0, stream>>>(vp + (size_t)layer * 131072, agg, h, bih, bhh);
    }

    k_conv<<<BSZ * ELEC, 64, 0, stream>>>(h, cw, cb, co);
    k_lin1<<<BSZ * 8, 128, 0, stream>>>(co, wt, fc1p);
    k_lin2<<<1, 128, 0, stream>>>(fc1p, l1b, l2w, l2b, out);
}

// Round 16
// 345.514 us; speedup vs baseline: 1.0866x; 1.0866x over previous
//
#include <hip/hip_runtime.h>
#include <math.h>

#define NN 65536
#define NE 1048576
#define HH 128
#define ELEC 32
#define BSZ 128
#define NB 512          // node buckets of 128

typedef unsigned short ushort_t;
typedef __bf16 bf16x8 __attribute__((ext_vector_type(8)));
typedef float f32x16 __attribute__((ext_vector_type(16)));

#define MFMA(A, B, C) __builtin_amdgcn_mfma_f32_32x32x16_bf16(A, B, C, 0, 0, 0)

__device__ __forceinline__ float sigm(float x) { return 1.f / (1.f + __expf(-x)); }
__device__ __forceinline__ float tanh_fast(float x) { return 2.f / (1.f + __expf(-2.f * x)) - 1.f; }

__device__ __forceinline__ float bf2f(ushort_t u) {
    union { unsigned int i; float f; } v; v.i = ((unsigned int)u) << 16; return v.f;
}
__device__ __forceinline__ ushort_t f2bf(float f) {
    union { float f; unsigned int i; } v; v.f = f;
    unsigned int r = (v.i + 0x7fffu + ((v.i >> 16) & 1u)) >> 16;
    return (ushort_t)r;
}

// ---------------- setup kernels ----------------

// h0 = pad(x) -> bf16 h[n][c]
__global__ void k_init(const float* __restrict__ x, ushort_t* __restrict__ h) {
    int i = blockIdx.x * 256 + threadIdx.x;   // n*128 + c
    int n = i >> 7, c = i & 127;
    float v = (c < 5) ? x[n * 5 + c] : 0.f;
    h[(size_t)n * 128 + c] = f2bf(v);
}

// per-bucket edge counts (LDS histogram -> few global adds)
__global__ __launch_bounds__(256) void k_bhist(const int* __restrict__ dst,
                                               int* __restrict__ bcnt) {
    __shared__ int hh[NB];
    int t = threadIdx.x;
    hh[t] = 0; hh[t + 256] = 0;
    __syncthreads();
    int e0 = blockIdx.x * 4096;
    #pragma unroll
    for (int i = 0; i < 16; ++i)
        atomicAdd(&hh[dst[e0 + i * 256 + t] >> 7], 1);
    __syncthreads();
    int c0 = hh[t];       if (c0) atomicAdd(&bcnt[t], c0);
    int c1 = hh[t + 256]; if (c1) atomicAdd(&bcnt[t + 256], c1);
}

// exclusive scan of 512 bucket counts
__global__ void k_bscan(const int* __restrict__ bcnt, int* __restrict__ boffs,
                        int* __restrict__ bcur) {
    __shared__ int s[NB];
    int t = threadIdx.x;          // 512 threads
    int v = bcnt[t];
    s[t] = v;
    __syncthreads();
    for (int d = 1; d < NB; d <<= 1) {
        int u = (t >= d) ? s[t - d] : 0;
        __syncthreads();
        s[t] += u;
        __syncthreads();
    }
    int ex = s[t] - v;
    boffs[t] = ex;
    bcur[t] = ex;
    if (t == NB - 1) boffs[NB] = s[t];
}

// bucket partition: per-(block,bucket) contiguous runs -> ~1x write amplification
__global__ __launch_bounds__(256) void k_bpart(const int* __restrict__ src,
        const int* __restrict__ dst, const float* __restrict__ ea,
        int* __restrict__ bcur, uint2* __restrict__ ebkt) {
    __shared__ int lcnt[NB];
    __shared__ int base[NB];
    __shared__ int lcur[NB];
    int t = threadIdx.x;
    lcnt[t] = 0; lcnt[t + 256] = 0;
    lcur[t] = 0; lcur[t + 256] = 0;
    __syncthreads();
    int e0 = blockIdx.x * 4096;
    #pragma unroll
    for (int i = 0; i < 16; ++i)
        atomicAdd(&lcnt[dst[e0 + i * 256 + t] >> 7], 1);
    __syncthreads();
    {
        int c = lcnt[t];
        base[t] = c ? atomicAdd(&bcur[t], c) : 0;
        c = lcnt[t + 256];
        base[t + 256] = c ? atomicAdd(&bcur[t + 256], c) : 0;
    }
    __syncthreads();
    #pragma unroll
    for (int i = 0; i < 16; ++i) {
        int e = e0 + i * 256 + t;
        int d = dst[e];
        int bk = d >> 7;
        int pos = base[bk] + atomicAdd(&lcur[bk], 1);
        uint2 pk;
        pk.x = (unsigned int)src[e] | ((unsigned int)(d & 127) << 16);
        pk.y = __float_as_uint(ea[e]);
        ebkt[pos] = pk;
    }
}

// bucket -> exact per-node CSC (writes land in bucket's 16KB window, L2-absorbed)
__global__ __launch_bounds__(256) void k_csc(const int* __restrict__ boffs,
        const uint2* __restrict__ ebkt, uint2* __restrict__ epack,
        int* __restrict__ offs) {
    __shared__ int cnt[128];
    __shared__ int s[128];
    __shared__ int base[128];
    int b = blockIdx.x, t = threadIdx.x;
    if (t < 128) cnt[t] = 0;
    __syncthreads();
    int e0 = boffs[b], e1 = boffs[b + 1];
    for (int i = e0 + t; i < e1; i += 256)
        atomicAdd(&cnt[(ebkt[i].x >> 16) & 127], 1);
    __syncthreads();
    if (t < 128) s[t] = cnt[t];
    __syncthreads();
    for (int d = 1; d < 128; d <<= 1) {
        int v = (t < 128 && t >= d) ? s[t - d] : 0;
        __syncthreads();
        if (t < 128) s[t] += v;
        __syncthreads();
    }
    if (t < 128) {
        int bs = e0 + s[t] - cnt[t];    // exclusive scan + bucket base
        base[t] = bs;
        offs[b * 128 + t] = bs;
        cnt[t] = 0;                     // reuse as cur
    }
    if (b == 0 && t == 255) offs[NN] = NE;
    __syncthreads();
    for (int i = e0 + t; i < e1; i += 256) {
        uint2 e = ebkt[i];
        int dl = (e.x >> 16) & 127;
        int pos = base[dl] + atomicAdd(&cnt[dl], 1);
        epack[pos] = e;
    }
}

// ---------------- weight prep ----------------
// G folded into GRU input weights: agg@Wih^T = (sum ew*h[src]) @ (G@Wih^T).
// b<1024: vp[l][512][256] frag-packed, frag idx = q*64 + ks*4 + g -> each wave's
// 64 B-frags are a contiguous 64KB stream. k<128 half = W1_l = Wih@G_l;
// else: lin1 weight transpose wt[k][c]
__global__ void k_prep(const float* __restrict__ wih, const float* __restrict__ whh,
                       const float* __restrict__ gw, const float* __restrict__ l1w,
                       ushort_t* __restrict__ vp, float* __restrict__ wt) {
    int b = blockIdx.x, t = threadIdx.x;
    if (b < 1024) {
        int i = b * 256 + t;              // l*131072 + rho*256 + k
        int l = i >> 17, r2 = i & 131071;
        int rho = r2 >> 8, k = r2 & 255;
        int q = rho >> 7, g = (rho >> 5) & 3, cc = rho & 31;
        int c = q * 32 + cc;
        float v;
        if (k >= 128) {
            if (g == 0)      v = whh[c * 128 + k - 128];
            else if (g == 1) v = whh[(128 + c) * 128 + k - 128];
            else if (g == 2) v = 0.f;
            else             v = whh[(256 + c) * 128 + k - 128];
        } else if (g == 3) {
            v = 0.f;
        } else {
            int crow = (g == 0) ? c : ((g == 1) ? 128 + c : 256 + c);
            const float* gr = gw + l * 16384 + k * 128;
            const float* wr = wih + crow * 128;
            float s = 0.f;
            for (int j = 0; j < 128; ++j) s = fmaf(gr[j], wr[j], s);
            v = s;
        }
        int ks = k >> 4, lh = (k >> 3) & 1, j = k & 7, lr = cc;
        vp[(size_t)l * 131072 + (size_t)(q * 64 + ks * 4 + g) * 512 + (lh * 32 + lr) * 8 + j] = f2bf(v);
    } else {
        int i = (b - 1024) * 256 + t;      // k*128 + c, k<2016
        int k = i >> 7, c = i & 127;
        wt[i] = l1w[c * 2016 + k];
    }
}

// ---------------- agg[n] = sum ew * h[esrc] -> bf16 agg[n][c] ----------------
// one wave per node, 4 quarter-wave groups x 4 edges per VMEM inst;
// traffic-bound at L3 random-row ceiling (R14: instruction economy was neutral)
__global__ __launch_bounds__(256) void k_gather(const ushort_t* __restrict__ h,
        const int* __restrict__ offs, const uint2* __restrict__ epack,
        ushort_t* __restrict__ agg) {
    int n = blockIdx.x * 4 + (threadIdx.x >> 6);
    int lane = threadIdx.x & 63;
    int g = lane >> 4;          // quarter-wave group
    int cj = (lane & 15) * 8;   // channel base
    int k0 = offs[n], k1 = offs[n + 1];
    float a[8];
    #pragma unroll
    for (int j = 0; j < 8; ++j) a[j] = 0.f;
    int kmax = k1 - 1;
    for (int k = k0; k < k1; k += 16) {
        #pragma unroll
        for (int st = 0; st < 4; ++st) {
            int ke = k + st * 4 + g;
            uint2 e = epack[ke <= kmax ? ke : kmax];
            float w = (ke < k1) ? __uint_as_float(e.y) : 0.f;
            bf16x8 u = *reinterpret_cast<const bf16x8*>(
                h + (size_t)(e.x & 0xFFFFu) * HH + cj);
            union { bf16x8 v; ushort_t s[8]; } uu; uu.v = u;
            #pragma unroll
            for (int j = 0; j < 8; ++j)
                a[j] = fmaf(w, bf2f(uu.s[j]), a[j]);
        }
    }
    #pragma unroll
    for (int j = 0; j < 8; ++j) {
        a[j] += __shfl_xor(a[j], 16, 64);
        a[j] += __shfl_xor(a[j], 32, 64);
    }
    if (lane < 16) {
        uint4 o;
        o.x = (unsigned int)f2bf(a[0]) | ((unsigned int)f2bf(a[1]) << 16);
        o.y = (unsigned int)f2bf(a[2]) | ((unsigned int)f2bf(a[3]) << 16);
        o.z = (unsigned int)f2bf(a[4]) | ((unsigned int)f2bf(a[5]) << 16);
        o.w = (unsigned int)f2bf(a[6]) | ((unsigned int)f2bf(a[7]) << 16);
        *reinterpret_cast<uint4*>(agg + (size_t)n * 128 + cj) = o;
    }
}

// ---------------- fused GRU via K=256 MFMA GEMM (L2-direct streaming B) ----------------
// block: 512 thr = 8 waves over 64 nodes; wave (q,s): V-rows q*128..+127, nodes s*32..+31.
// Twin waves (q,0)/(q,1) share B stream via L1; per-wave B reads are a contiguous
// 64KB stream (frag idx q*64+ks*4+g). acc=64 AGPRs + ~56 VGPRs -> (512,4);
// (512,8) forces a 64-reg/wave budget and spills the accumulators (41ms, R11);
// LDS double-buffering B regressed (50 µs + bank conflicts, R15).
__global__ __launch_bounds__(512, 4) void k_gru(const ushort_t* __restrict__ vp,
        const ushort_t* __restrict__ agg, ushort_t* __restrict__ h,
        const float* __restrict__ bih, const float* __restrict__ bhh) {
    int t = threadIdx.x;
    int lane = t & 63, w = t >> 6;
    int q = w >> 1, s = w & 1;
    int lr = lane & 31, lh = lane >> 5;
    int n0 = blockIdx.x * 64 + s * 32;
    f32x16 acc[4];
    #pragma unroll
    for (int g = 0; g < 4; ++g)
        #pragma unroll
        for (int r = 0; r < 16; ++r) acc[g][r] = 0.f;

    size_t rowA = (size_t)(n0 + lr) * 128;
    const ushort_t* vq = vp + (size_t)q * 64 * 512;
    #pragma unroll
    for (int ks = 0; ks < 16; ++ks) {
        bf16x8 a;
        if (ks < 8) a = *reinterpret_cast<const bf16x8*>(agg + rowA + ks * 16 + lh * 8);
        else        a = *reinterpret_cast<const bf16x8*>(h + rowA + (ks - 8) * 16 + lh * 8);
        #pragma unroll
        for (int g = 0; g < 4; ++g) {
            bf16x8 b = *reinterpret_cast<const bf16x8*>(vq + (size_t)(ks * 4 + g) * 512 + lane * 8);
            acc[g] = MFMA(a, b, acc[g]);
        }
    }

    __syncthreads();   // all waves done reading h before in-place overwrite

    int c = q * 32 + lr;
    float brz = bih[c] + bhh[c];
    float bzz = bih[128 + c] + bhh[128 + c];
    float bin = bih[256 + c];
    float bhn = bhh[256 + c];
    #pragma unroll
    for (int r = 0; r < 16; ++r) {
        int node = n0 + (r & 3) + 8 * (r >> 2) + 4 * lh;
        float rg = sigm(acc[0][r] + brz);
        float zg = sigm(acc[1][r] + bzz);
        float nn = tanh_fast(acc[2][r] + bin + rg * (acc[3][r] + bhn));
        size_t idx = (size_t)node * 128 + c;
        float hold = bf2f(h[idx]);
        float hnew = (1.f - zg) * nn + zg * hold;
        h[idx] = f2bf(hnew);
    }
}

// ---------------- relu + rearrange + conv1d(stride2,k3) + relu ----------------
__global__ __launch_bounds__(64) void k_conv(const ushort_t* __restrict__ h,
        const float* __restrict__ cw, const float* __restrict__ cb,
        float* __restrict__ co) {
    __shared__ float tile[16 * 128];
    __shared__ float w[48];
    int be = blockIdx.x;
    int b = be >> 5, e = be & 31;
    int t = threadIdx.x;
    if (t < 48) w[t] = cw[t];
    #pragma unroll
    for (int i = 0; i < 8; ++i) {
        int f = t + i * 64;             // 0..511 groups of 4 channels
        int g = f >> 5, c4 = f & 31;
        size_t idx = (size_t)(b * 512 + g * 32 + e) * 128 + c4 * 4;
        ushort4 vh4 = *reinterpret_cast<const ushort4*>(h + idx);
        float* dst = tile + g * 128 + c4 * 4;
        dst[0] = fmaxf(bf2f(vh4.x), 0.f);
        dst[1] = fmaxf(bf2f(vh4.y), 0.f);
        dst[2] = fmaxf(bf2f(vh4.z), 0.f);
        dst[3] = fmaxf(bf2f(vh4.w), 0.f);
    }
    __syncthreads();
    if (t < 63) {
        float s = cb[0];
        #pragma unroll
        for (int g = 0; g < 16; ++g) {
            const float* p = tile + g * 128 + 2 * t;
            s = fmaf(p[0], w[g * 3 + 0], s);
            s = fmaf(p[1], w[g * 3 + 1], s);
            s = fmaf(p[2], w[g * 3 + 2], s);
        }
        co[b * 2016 + e * 63 + t] = fmaxf(s, 0.f);
    }
}

// ---------------- lin1: split-K, coalesced transposed weights, atomic reduce ----------------
__global__ __launch_bounds__(128) void k_lin1(const float* __restrict__ co,
        const float* __restrict__ wt, float* __restrict__ fc1) {
    int b = blockIdx.x >> 3;
    int ks = blockIdx.x & 7;
    int c = threadIdx.x;
    const float* cb_ = co + b * 2016 + ks * 252;
    const float* wb = wt + (ks * 252) * 128 + c;
    float s = 0.f;
    #pragma unroll 4
    for (int k = 0; k < 252; ++k)
        s = fmaf(wb[k * 128], cb_[k], s);
    atomicAdd(&fc1[b * 128 + c], s);
}

// ---------------- lin2 + softmax (bias+relu of lin1 folded in) ----------------
__global__ __launch_bounds__(128) void k_lin2(const float* __restrict__ fc1,
        const float* __restrict__ l1b, const float* __restrict__ w,
        const float* __restrict__ bias, float* __restrict__ out) {
    int b = threadIdx.x;
    float s0 = bias[0], s1 = bias[1], s2 = bias[2];
    const float* v = fc1 + b * 128;
    for (int k = 0; k < 128; ++k) {
        float x = fmaxf(v[k] + l1b[k], 0.f);
        s0 = fmaf(x, w[k], s0);
        s1 = fmaf(x, w[128 + k], s1);
        s2 = fmaf(x, w[256 + k], s2);
    }
    float mx = fmaxf(s0, fmaxf(s1, s2));
    float e0 = __expf(s0 - mx), e1 = __expf(s1 - mx), e2 = __expf(s2 - mx);
    float inv = 1.f / (e0 + e1 + e2);
    out[b * 3 + 0] = e0 * inv;
    out[b * 3 + 1] = e1 * inv;
    out[b * 3 + 2] = e2 * inv;
}

extern "C" void kernel_launch(void* const* d_in, const int* in_sizes, int n_in,
                              void* d_out, int out_size, void* d_ws, size_t ws_size,
                              hipStream_t stream) {
    const float* x   = (const float*)d_in[0];
    const int*   ei  = (const int*)d_in[1];
    const float* ea  = (const float*)d_in[2];
    const float* gw  = (const float*)d_in[4];
    const float* wih = (const float*)d_in[5];
    const float* whh = (const float*)d_in[6];
    const float* bih = (const float*)d_in[7];
    const float* bhh = (const float*)d_in[8];
    const float* cw  = (const float*)d_in[9];
    const float* cb  = (const float*)d_in[10];
    const float* l1w = (const float*)d_in[11];
    const float* l1b = (const float*)d_in[12];
    const float* l2w = (const float*)d_in[13];
    const float* l2b = (const float*)d_in[14];
    float* out = (float*)d_out;

    char* p = (char*)d_ws;
    ushort_t* h   = (ushort_t*)p; p += (size_t)NN * 128 * 2;      // 16.7 MB
    ushort_t* agg = (ushort_t*)p; p += (size_t)NN * 128 * 2;      // 16.7 MB
    ushort_t* vp  = (ushort_t*)p; p += 2 * 512 * 256 * 2;         // frag-packed V (G folded), per layer
    uint2* ebkt   = (uint2*)p;   p += (size_t)NE * 8;             // 8.4 MB
    uint2* epack  = (uint2*)p;   p += (size_t)NE * 8;             // 8.4 MB
    float* wt  = (float*)p; p += 2016 * 128 * 4;                  // lin1 W^T
    float* co  = (float*)p; p += (size_t)BSZ * 2016 * 4;
    float* fc1 = (float*)p; p += (size_t)BSZ * HH * 4;
    int* bcnt  = (int*)p; p += NB * 4;
    int* boffs = (int*)p; p += (NB + 1) * 4;
    int* bcur  = (int*)p; p += NB * 4;
    int* offs  = (int*)p; p += (size_t)(NN + 1) * 4;

    const int* src = ei;
    const int* dst = ei + NE;

    k_prep<<<2032, 256, 0, stream>>>(wih, whh, gw, l1w, vp, wt);
    hipMemsetAsync(bcnt, 0, NB * 4, stream);
    hipMemsetAsync(fc1, 0, (size_t)BSZ * HH * 4, stream);
    k_bhist<<<256, 256, 0, stream>>>(dst, bcnt);
    k_bscan<<<1, 512, 0, stream>>>(bcnt, boffs, bcur);
    k_bpart<<<256, 256, 0, stream>>>(src, dst, ea, bcur, ebkt);
    k_csc<<<NB, 256, 0, stream>>>(boffs, ebkt, epack, offs);
    k_init<<<(NN * 128) / 256, 256, 0, stream>>>(x, h);

    for (int layer = 0; layer < 2; ++layer) {
        k_gather<<<NN / 4, 256, 0, stream>>>(h, offs, epack, agg);
        k_gru<<<NN / 64, 512, 0, stream>>>(vp + (size_t)layer * 131072, agg, h, bih, bhh);
    }

    k_conv<<<BSZ * ELEC, 64, 0, stream>>>(h, cw, cb, co);
    k_lin1<<<BSZ * 8, 128, 0, stream>>>(co, wt, fc1);
    k_lin2<<<1, 128, 0, stream>>>(fc1, l1b, l2w, l2b, out);
}